// Round 1
// baseline (24.899 us; speedup 1.0000x reference)
//
#include <hip/hip_runtime.h>
#include <math.h>

#define FDIM 14
#define HBINS 7
#define WBINS 7

// One block per output cell (n, bh, bw). Thread t handles channels [4t, 4t+4).
__global__ __launch_bounds__(128) void roi_pool_kernel(
    const float* __restrict__ fm,    // [F, F, C]
    const float* __restrict__ rois,  // [N, 4]
    float* __restrict__ out,         // [N, H, W, C]
    int C)                           // channels (multiple of 4)
{
    const int cell = blockIdx.x;                 // n*(H*W) + bh*W + bw
    const int n    = cell / (HBINS * WBINS);
    const int rem  = cell - n * (HBINS * WBINS);
    const int bh   = rem / WBINS;
    const int bw   = rem - bh * WBINS;

    const int C4 = C >> 2;
    const float4* fm4  = (const float4*)fm;
    float4*       out4 = (float4*)out;

    // ROI params (wave-uniform per block; redundant compute across lanes is fine)
    const float4 r = ((const float4*)rois)[n];
    const int x_min = (int)floorf((float)FDIM * r.x);
    const int y_min = (int)floorf((float)FDIM * r.y);
    const int x_max = (int)floorf((float)FDIM * r.z);
    const int y_max = (int)floorf((float)FDIM * r.w);
    const int rw = x_max - x_min;
    const int rh = y_max - y_min;
    const int sw = rw / WBINS;   // rw,rh >= 0 in-distribution; if negative, loops below are empty anyway
    const int sh = rh / HBINS;

    // Input-row range [r0, r1) and column range [c0, c1) mapping to this bin
    // (TF binning: bh = min(ry // sh, H-1) for sh>0, else H-1).
    int r0, r1, c0, c1;
    if (sh > 0) { r0 = bh * sh; r1 = (bh < HBINS - 1) ? (bh + 1) * sh : rh; }
    else        { r0 = 0;       r1 = (bh == HBINS - 1) ? rh : 0; }
    if (sw > 0) { c0 = bw * sw; c1 = (bw < WBINS - 1) ? (bw + 1) * sw : rw; }
    else        { c0 = 0;       c1 = (bw == WBINS - 1) ? rw : 0; }

    // Intersect with the feature-map grid: 0 <= y_min+ry < F, 0 <= x_min+rx < F
    r0 = max(r0, -y_min);  r1 = min(r1, FDIM - y_min);
    c0 = max(c0, -x_min);  c1 = min(c1, FDIM - x_min);

    const int t = threadIdx.x;   // channel chunk
    float4 acc = make_float4(-INFINITY, -INFINITY, -INFINITY, -INFINITY);

    for (int ry = r0; ry < r1; ++ry) {
        const int ys = y_min + ry;
        const float4* row = fm4 + (size_t)(ys * FDIM) * C4;
        for (int rx = c0; rx < c1; ++rx) {
            const int xs = x_min + rx;
            const float4 v = row[(size_t)xs * C4 + t];
            acc.x = fmaxf(acc.x, v.x);
            acc.y = fmaxf(acc.y, v.y);
            acc.z = fmaxf(acc.z, v.z);
            acc.w = fmaxf(acc.w, v.w);
        }
    }

    out4[(size_t)cell * C4 + t] = acc;
}

extern "C" void kernel_launch(void* const* d_in, const int* in_sizes, int n_in,
                              void* d_out, int out_size, void* d_ws, size_t ws_size,
                              hipStream_t stream) {
    const float* fm   = (const float*)d_in[0];   // [1, 14, 14, C]
    const float* rois = (const float*)d_in[1];   // [1, N, 4]

    const int C = in_sizes[0] / (FDIM * FDIM);   // 512
    const int N = in_sizes[1] / 4;               // 1024

    float* out = (float*)d_out;                  // [N, 7, 7, C]

    const int blocks  = N * HBINS * WBINS;       // 50176
    const int threads = C / 4;                   // 128

    roi_pool_kernel<<<blocks, threads, 0, stream>>>(fm, rois, out, C);
}